// Round 3
// baseline (1045.812 us; speedup 1.0000x reference)
//
#include <hip/hip_runtime.h>

#define S_LEN 2048
#define DMODEL 1024
#define NH 16
#define DH 64
#define FFDIM 4096

typedef __bf16 bf16x8 __attribute__((ext_vector_type(8)));
typedef float f32x4 __attribute__((ext_vector_type(4)));
typedef unsigned short ushort_t;

#define AS1 __attribute__((address_space(1)))
#define AS3 __attribute__((address_space(3)))

__device__ __forceinline__ void gll16(const void* g, void* l) {
  __builtin_amdgcn_global_load_lds((AS1 const void*)g, (AS3 void*)l, 16, 0, 0);
}

__device__ __forceinline__ unsigned short f2b(float f){
  unsigned u = __builtin_bit_cast(unsigned, f);
  u = (u + 0x7FFFu + ((u >> 16) & 1u)) >> 16;
  return (unsigned short)u;
}

__device__ __forceinline__ float b2f(unsigned short us){
  return __builtin_bit_cast(float, (unsigned)us << 16);
}

// packed bf16 convert: dst.lo = bf16(lo), dst.hi = bf16(hi) (RNE)
__device__ __forceinline__ unsigned cvt_pk_bf16(float lo, float hi){
  unsigned r;
  asm("v_cvt_pk_bf16_f32 %0, %1, %2" : "=v"(r) : "v"(lo), "v"(hi));
  return r;
}

__device__ __forceinline__ float gelu_exact(float x){
  return 0.5f * x * (1.0f + erff(x * 0.70710678118654752f));
}

__device__ __forceinline__ f32x4 mfma16(bf16x8 a, bf16x8 b, f32x4 c){
  return __builtin_amdgcn_mfma_f32_16x16x32_bf16(a, b, c, 0, 0, 0);
}

// ---------------- all 6 weight transposes in ONE launch ----------------
__global__ __launch_bounds__(256) void tconv6(
    const float* __restrict__ s0, const float* __restrict__ s1,
    const float* __restrict__ s2, const float* __restrict__ s3,
    const float* __restrict__ s4, const float* __restrict__ s5,
    ushort_t* __restrict__ d0, ushort_t* __restrict__ d1,
    ushort_t* __restrict__ d2, ushort_t* __restrict__ d3,
    ushort_t* __restrict__ d4, ushort_t* __restrict__ d5)
{
  __shared__ float tile[32][33];
  int bx = blockIdx.x;
  const float* W; ushort_t* Wt; int K, N, n0, k0;
  if (bx < 4096) {
    int seg = bx >> 10, t_ = bx & 1023;
    W = (seg == 0) ? s0 : (seg == 1) ? s1 : (seg == 2) ? s2 : s3;
    Wt = (seg == 0) ? d0 : (seg == 1) ? d1 : (seg == 2) ? d2 : d3;
    K = 1024; N = 1024; n0 = (t_ & 31) * 32; k0 = (t_ >> 5) * 32;
  } else if (bx < 8192) {
    int t_ = bx - 4096;
    W = s4; Wt = d4; K = 1024; N = 4096;
    n0 = (t_ & 127) * 32; k0 = (t_ >> 7) * 32;
  } else {
    int t_ = bx - 8192;
    W = s5; Wt = d5; K = 4096; N = 1024;
    n0 = (t_ & 31) * 32; k0 = (t_ >> 5) * 32;
  }
  int tx = threadIdx.x, ty = threadIdx.y;
#pragma unroll
  for (int i = 0; i < 4; ++i)
    tile[ty + i*8][tx] = W[(size_t)(k0 + ty + i*8) * N + n0 + tx];
  __syncthreads();
#pragma unroll
  for (int i = 0; i < 4; ++i)
    Wt[(size_t)(n0 + ty + i*8) * K + k0 + tx] = f2b(tile[tx][ty + i*8]);
}

// ---------------- layernorm (fp32 in) -> bf16 out ----------------
__global__ __launch_bounds__(256) void ln_kernel(
    const float* __restrict__ x, const float* __restrict__ g,
    const float* __restrict__ bt, ushort_t* __restrict__ out)
{
  int row = blockIdx.x;
  int t = threadIdx.x;
  const float4 v = *(const float4*)&x[(size_t)row * DMODEL + t * 4];
  float s = v.x + v.y + v.z + v.w;
  float s2 = v.x*v.x + v.y*v.y + v.z*v.z + v.w*v.w;
#pragma unroll
  for (int d = 1; d < 64; d <<= 1) {
    s  += __shfl_xor(s,  d, 64);
    s2 += __shfl_xor(s2, d, 64);
  }
  __shared__ float red[8];
  int w = t >> 6;
  if ((t & 63) == 0) { red[w] = s; red[4 + w] = s2; }
  __syncthreads();
  s  = red[0] + red[1] + red[2] + red[3];
  s2 = red[4] + red[5] + red[6] + red[7];
  float mean = s * (1.0f / DMODEL);
  float var  = s2 * (1.0f / DMODEL) - mean * mean;
  float rstd = rsqrtf(var + 1e-5f);
  float4 gg = *(const float4*)&g[t * 4];
  float4 bb = *(const float4*)&bt[t * 4];
  ushort4 o;
  o.x = f2b((v.x - mean) * rstd * gg.x + bb.x);
  o.y = f2b((v.y - mean) * rstd * gg.y + bb.y);
  o.z = f2b((v.z - mean) * rstd * gg.z + bb.z);
  o.w = f2b((v.w - mean) * rstd * gg.w + bb.w);
  *(ushort4*)&out[(size_t)row * DMODEL + t * 4] = o;
}

// ---------------- bias precompute, fragment-ordered ----------------
// FB[bh][jt][qw][n][lane][r]  (elem = ((((bh*32+jt)*128+qw)*4+n)*64+l)*4+r)
// where q = qw*16 + lr, j = jt*64 + n*16 + lg*4 + r, l = lg*16 + lr
__global__ __launch_bounds__(256) void bias_head_kernel(
    const float* __restrict__ ab, const float* __restrict__ mc,
    const unsigned char* __restrict__ kp,
    const float* __restrict__ Ws, const float* __restrict__ bs,
    const float* __restrict__ Wm, const float* __restrict__ bm,
    ushort_t* __restrict__ bp)
{
  int bi = blockIdx.x;            // b*S + i
  int b = bi >> 11;
  int i = bi & (S_LEN - 1);
  int qw = i >> 4, lr = i & 15;
  int t = threadIdx.x;
  int j0 = t * 8;
  int jt = t >> 3;
  int n  = (t & 7) >> 1;
  int lg_a = ((t & 7) * 2) & 3;   // jj 0..3
  int lg_b = lg_a + 1;            // jj 4..7
  float av[24];
  const float4* A4 = (const float4*)(ab + ((size_t)bi * S_LEN + j0) * 3);
#pragma unroll
  for (int u = 0; u < 6; ++u) {
    float4 x = A4[u];
    av[u*4] = x.x; av[u*4+1] = x.y; av[u*4+2] = x.z; av[u*4+3] = x.w;
  }
  float mv[8];
  const float4* M4 = (const float4*)(mc + (size_t)bi * S_LEN + j0);
#pragma unroll
  for (int u = 0; u < 2; ++u) {
    float4 x = M4[u];
    mv[u*4] = x.x; mv[u*4+1] = x.y; mv[u*4+2] = x.z; mv[u*4+3] = x.w;
  }
  unsigned long long kq = *(const unsigned long long*)(kp + (size_t)b * S_LEN + j0);
#pragma unroll
  for (int h = 0; h < NH; ++h) {
    float w0 = Ws[h], w1 = Ws[NH + h], w2 = Ws[2*NH + h];
    float wm = Wm[h], cc = bs[h] + bm[h];
    float v[8];
#pragma unroll
    for (int j = 0; j < 8; ++j) {
      float vv = av[j*3]*w0 + av[j*3+1]*w1 + av[j*3+2]*w2 + mv[j]*wm + cc;
      if ((kq >> (8*j)) & 1ull) vv = -1e9f;
      v[j] = vv;
    }
    size_t base = ((((size_t)(b*NH + h) * 32 + jt) * 128 + qw) * 4 + n) * 256;
    uint2 u0, u1;
    u0.x = cvt_pk_bf16(v[0], v[1]); u0.y = cvt_pk_bf16(v[2], v[3]);
    u1.x = cvt_pk_bf16(v[4], v[5]); u1.y = cvt_pk_bf16(v[6], v[7]);
    *(uint2*)&bp[base + (size_t)(lg_a*16 + lr) * 4] = u0;
    *(uint2*)&bp[base + (size_t)(lg_b*16 + lr) * 4] = u1;
  }
}

// ---------------- bf16 GEMM, 128x128 tile, 2-phase dbuf ----------------
// MODE 3: out bf16 = gelu(acc + bias)
// MODE 4: fused QKV: N=3072; seg0->o0 bf16, seg1->o1 bf16, seg2->o2 vt layout
template<int MODE>
__global__ __launch_bounds__(256) void gemm_bt(
    const ushort_t* __restrict__ A, const ushort_t* __restrict__ Bt,
    const float* __restrict__ b0p, const float* __restrict__ b1p,
    const float* __restrict__ b2p,
    void* __restrict__ o0, void* __restrict__ o1, void* __restrict__ o2,
    int M, int N, int K)
{
  __shared__ ushort_t sh[2][8192];
  int t = threadIdx.x;
  int m0 = blockIdx.y * 128, n0 = blockIdx.x * 128;
  int w = t >> 6, l = t & 63, lr = l & 15, lg = l >> 4;
  int wr = (w >> 1) * 64, wc = (w & 1) * 64;

  const ushort_t* srcp[4];
  int dsto[4];
#pragma unroll
  for (int j = 0; j < 4; ++j) {
    int c = j * 4 + w;
    int o = c * 1024 + l * 16;
    if (c < 8)
      srcp[j] = &A[(size_t)(m0 + (o >> 6)) * K + ((o & 63) >> 1)];
    else {
      int o2 = o - 8192;
      srcp[j] = &Bt[(size_t)(n0 + (o2 >> 6)) * K + ((o2 & 63) >> 1)];
    }
    dsto[j] = o;
  }

#define GSTAGE(bi, kk) do { \
  _Pragma("unroll") \
  for (int j = 0; j < 4; ++j) gll16(srcp[j] + (kk), (char*)sh[bi] + dsto[j]); \
} while (0)

  GSTAGE(0, 0);
  __syncthreads();
  f32x4 acc[4][4] = {};
  int cur = 0;
  for (int k0 = 0; k0 < K; k0 += 32) {
    if (k0 + 32 < K) GSTAGE(cur ^ 1, k0 + 32);
    const ushort_t* s = sh[cur];
    bf16x8 af[4], bfr[4];
#pragma unroll
    for (int a = 0; a < 4; ++a)
      af[a] = *(const bf16x8*)&s[(wr + a * 16 + lr) * 32 + lg * 8];
#pragma unroll
    for (int b = 0; b < 4; ++b)
      bfr[b] = *(const bf16x8*)&s[4096 + (wc + b * 16 + lr) * 32 + lg * 8];
    __builtin_amdgcn_s_setprio(1);
#pragma unroll
    for (int a = 0; a < 4; ++a)
#pragma unroll
      for (int b = 0; b < 4; ++b)
        acc[a][b] = mfma16(af[a], bfr[b], acc[a][b]);
    __builtin_amdgcn_s_setprio(0);
    __syncthreads();
    cur ^= 1;
  }
#undef GSTAGE

  if (MODE == 3) {
    ushort_t* out = (ushort_t*)o0;
#pragma unroll
    for (int a = 0; a < 4; ++a)
#pragma unroll
      for (int b = 0; b < 4; ++b) {
        int gn = n0 + wc + b * 16 + lr;
        float bv = b0p[gn];
#pragma unroll
        for (int r = 0; r < 4; ++r) {
          int gm = m0 + wr + a * 16 + lg * 4 + r;
          out[(size_t)gm * N + gn] = f2b(gelu_exact(acc[a][b][r] + bv));
        }
      }
  } else { // MODE 4
    int seg = n0 >> 10;
    int nb0 = n0 & 1023;
    const float* bi = (seg == 0) ? b0p : (seg == 1) ? b1p : b2p;
    if (seg < 2) {
      ushort_t* out = (ushort_t*)((seg == 0) ? o0 : o1);
#pragma unroll
      for (int a = 0; a < 4; ++a)
#pragma unroll
        for (int b = 0; b < 4; ++b) {
          int nn = nb0 + wc + b * 16 + lr;
          float bv = bi[nn];
#pragma unroll
          for (int r = 0; r < 4; ++r) {
            int gm = m0 + wr + a * 16 + lg * 4 + r;
            out[(size_t)gm * DMODEL + nn] = f2b(acc[a][b][r] + bv);
          }
        }
    } else {
      ushort_t* out = (ushort_t*)o2;    // vt[b][h][dh][s]
#pragma unroll
      for (int a = 0; a < 4; ++a)
#pragma unroll
        for (int b = 0; b < 4; ++b) {
          int nn = nb0 + wc + b * 16 + lr;
          int gm = m0 + wr + a * 16 + lg * 4;
          float bv = bi[nn];
          ushort4 pk;
          pk.x = f2b(acc[a][b][0] + bv);
          pk.y = f2b(acc[a][b][1] + bv);
          pk.z = f2b(acc[a][b][2] + bv);
          pk.w = f2b(acc[a][b][3] + bv);
          size_t addr = (((size_t)(gm >> 11) * NH + (nn >> 6)) * DH + (nn & 63)) * S_LEN
                        + (gm & (S_LEN - 1));
          *(ushort4*)&out[addr] = pk;
        }
    }
  }
}

// ---------------- bf16 GEMM, 128x64 tile, fp32 out = acc + bias + res ----------------
__global__ __launch_bounds__(256) void gemm64_res(
    const ushort_t* __restrict__ A, const ushort_t* __restrict__ Bt,
    const float* __restrict__ bias, const float* __restrict__ res,
    float* __restrict__ out, int M, int N, int K)
{
  __shared__ ushort_t sh[2][6144];   // A [128][32] @0, B [64][32] @4096 (ushorts)
  int t = threadIdx.x;
  int m0 = blockIdx.y * 128, n0 = blockIdx.x * 64;
  int w = t >> 6, l = t & 63, lr = l & 15, lg = l >> 4;
  int wr = (w >> 1) * 64, wc = (w & 1) * 32;

  const ushort_t* srcp[3];
  int dsto[3];
#pragma unroll
  for (int j = 0; j < 3; ++j) {
    int c = j * 4 + w;
    int o = c * 1024 + l * 16;
    if (c < 8)
      srcp[j] = &A[(size_t)(m0 + (o >> 6)) * K + ((o & 63) >> 1)];
    else {
      int o2 = o - 8192;
      srcp[j] = &Bt[(size_t)(n0 + (o2 >> 6)) * K + ((o2 & 63) >> 1)];
    }
    dsto[j] = o;
  }

#define GSTAGE64(bi, kk) do { \
  _Pragma("unroll") \
  for (int j = 0; j < 3; ++j) gll16(srcp[j] + (kk), (char*)sh[bi] + dsto[j]); \
} while (0)

  GSTAGE64(0, 0);
  __syncthreads();
  f32x4 acc[4][2] = {};
  int cur = 0;
  for (int k0 = 0; k0 < K; k0 += 32) {
    if (k0 + 32 < K) GSTAGE64(cur ^ 1, k0 + 32);
    const ushort_t* s = sh[cur];
    bf16x8 af[4], bfr[2];
#pragma unroll
    for (int a = 0; a < 4; ++a)
      af[a] = *(const bf16x8*)&s[(wr + a * 16 + lr) * 32 + lg * 8];
#pragma unroll
    for (int b = 0; b < 2; ++b)
      bfr[b] = *(const bf16x8*)&s[4096 + (wc + b * 16 + lr) * 32 + lg * 8];
    __builtin_amdgcn_s_setprio(1);
#pragma unroll
    for (int a = 0; a < 4; ++a)
#pragma unroll
      for (int b = 0; b < 2; ++b)
        acc[a][b] = mfma16(af[a], bfr[b], acc[a][b]);
    __builtin_amdgcn_s_setprio(0);
    __syncthreads();
    cur ^= 1;
  }
#undef GSTAGE64

#pragma unroll
  for (int a = 0; a < 4; ++a)
#pragma unroll
    for (int b = 0; b < 2; ++b) {
      int gn = n0 + wc + b * 16 + lr;
      float bv = bias[gn];
#pragma unroll
      for (int r = 0; r < 4; ++r) {
        int gm = m0 + wr + a * 16 + lg * 4 + r;
        out[(size_t)gm * N + gn] = acc[a][b][r] + bv + res[(size_t)gm * N + gn];
      }
    }
}

// ---------------- fused flash attention, swapped-QK, swizzled LDS, dbuf ----------------
__global__ __launch_bounds__(256) void attn_kernel(
    const ushort_t* __restrict__ q, const ushort_t* __restrict__ k,
    const ushort_t* __restrict__ vt, const ushort_t* __restrict__ bp,
    ushort_t* __restrict__ att)
{
  __shared__ ushort_t kbuf[2][4096];   // [64 rows][64 cols] bf16, content pre-swizzled
  __shared__ ushort_t vbuf[2][4096];
  __shared__ ushort_t p_lds[4096];     // [64 q][64 j] bf16, swizzled
  int bh = blockIdx.y;
  int b = bh >> 4, h = bh & 15;
  int i0 = blockIdx.x * 64;
  int t = threadIdx.x, w = t >> 6, l = t & 63;
  int lr = l & 15, lg = l >> 4;
  int rho = lr & 7;
  const float scale = 0.125f;

  // staging geometry (per thread): it in {0,1}
  int srow0 = t >> 3, srow1 = 32 + (t >> 3);
  int c16 = t & 7;
  size_t kb0 = (size_t)b * S_LEN * DMODEL + h * DH;
  size_t vb0 = (size_t)(b * NH + h) * DH * S_LEN;
  size_t koff0 = (size_t)srow0 * DMODEL + ((c16 ^ (srow0 & 7)) << 3);
  size_t koff1 = (size_t)srow1 * DMODEL + ((c16 ^ (srow1 & 7)) << 3);
  size_t voff0 = (size_t)srow0 * S_LEN + ((c16 ^ (srow0 & 7)) << 3);
  size_t voff1 = (size_t)srow1 * S_LEN + ((c16 ^ (srow1 & 7)) << 3);
  int do0 = t * 8, do1 = 2048 + t * 8;

#define STAGE_KV(bi, j0_) do { \
  size_t kr = kb0 + (size_t)(j0_) * DMODEL; \
  size_t vr = vb0 + (size_t)(j0_); \
  gll16(k + kr + koff0, &kbuf[bi][do0]); \
  gll16(k + kr + koff1, &kbuf[bi][do1]); \
  gll16(vt + vr + voff0, &vbuf[bi][do0]); \
  gll16(vt + vr + voff1, &vbuf[bi][do1]); \
} while (0)

  // Q fragments (B-operand): lane lr -> q-row, lg -> k-chunk
  int qrow = i0 + w * 16 + lr;
  size_t qbase = (size_t)(b * S_LEN + qrow) * DMODEL + h * DH;
  bf16x8 aq0 = *(const bf16x8*)&q[qbase + lg * 8];
  bf16x8 aq1 = *(const bf16x8*)&q[qbase + 32 + lg * 8];

  // fragment-ordered bias base: FB[bh][jt][qw][n][l][4]
  int qw = blockIdx.x * 4 + w;
  size_t fb0 = (((size_t)bh * 32) * 128 + qw) * 1024 + l * 4;

  f32x4 acc_o[4] = {};
  float m_run = -1e30f, l_run = 0.0f;

  STAGE_KV(0, 0);
  __syncthreads();

  for (int jt = 0; jt < S_LEN / 64; ++jt) {
    int cur = jt & 1;
    if (jt + 1 < S_LEN / 64) STAGE_KV(cur ^ 1, (jt + 1) * 64);

    // ---- QK^T (swapped: A=K rows, B=Q) ----
    const char* kbc = (const char*)kbuf[cur];
    f32x4 acc_s[4] = {};
    __builtin_amdgcn_s_setprio(1);
#pragma unroll
    for (int n = 0; n < 4; ++n) {
      const char* rb = kbc + (n * 16 + lr) * 128;
      bf16x8 k0 = *(const bf16x8*)(rb + ((lg ^ rho) << 4));
      bf16x8 k1 = *(const bf16x8*)(rb + (((4 + lg) ^ rho) << 4));
      acc_s[n] = mfma16(k0, aq0, acc_s[n]);
      acc_s[n] = mfma16(k1, aq1, acc_s[n]);
    }
    __builtin_amdgcn_s_setprio(0);

    // ---- bias + online softmax (lane owns one q-row, 16 k-values) ----
    float p[16];
    size_t fb = fb0 + (size_t)jt * 131072;
#pragma unroll
    for (int n = 0; n < 4; ++n) {
      uint2 raw = *(const uint2*)&bp[fb + n * 256];
      p[n*4+0] = fmaf(acc_s[n][0], scale, b2f((unsigned short)(raw.x & 0xFFFF)));
      p[n*4+1] = fmaf(acc_s[n][1], scale, b2f((unsigned short)(raw.x >> 16)));
      p[n*4+2] = fmaf(acc_s[n][2], scale, b2f((unsigned short)(raw.y & 0xFFFF)));
      p[n*4+3] = fmaf(acc_s[n][3], scale, b2f((unsigned short)(raw.y >> 16)));
    }
    float t8[8], t4[4];
#pragma unroll
    for (int i = 0; i < 8; ++i) t8[i] = fmaxf(p[i], p[i + 8]);
#pragma unroll
    for (int i = 0; i < 4; ++i) t4[i] = fmaxf(t8[i], t8[i + 4]);
    float mx = fmaxf(fmaxf(t4[0], t4[1]), fmaxf(t4[2], t4[3]));
    mx = fmaxf(mx, __shfl_xor(mx, 16, 64));
    mx = fmaxf(mx, __shfl_xor(mx, 32, 64));
    float mnew = fmaxf(m_run, mx);
    float sf = __expf(m_run - mnew);
    m_run = mnew;
#pragma unroll
    for (int i = 0; i < 16; ++i) p[i] = __expf(p[i] - mnew);
    float s8[8], s4[4];
#pragma unroll
    for (int i = 0; i < 8; ++i) s8[i] = p[i] + p[i + 8];
#pragma unroll
    for (int i = 0; i < 4; ++i) s4[i] = s8[i] + s8[i + 4];
    float ls = (s4[0] + s4[1]) + (s4[2] + s4[3]);
    ls += __shfl_xor(ls, 16, 64);
    ls += __shfl_xor(ls, 32, 64);
    l_run = l_run * sf + ls;

    // broadcast rescale factor to acc_o rows (row = lg*4 + r, held by lane lr = that row)
    float sfr[4];
#pragma unroll
    for (int r = 0; r < 4; ++r) sfr[r] = __shfl(sf, lg * 4 + r, 64);
#pragma unroll
    for (int nd = 0; nd < 4; ++nd)
#pragma unroll
      for (int r = 0; r < 4; ++r) acc_o[nd][r] *= sfr[r];

    // ---- pack P -> swizzled LDS (wave-private rows) ----
    char* pb = (char*)p_lds + (w * 16 + lr) * 128;
#pragma unroll
    for (int n = 0; n < 4; ++n) {
      uint2 pk2;
      pk2.x = cvt_pk_bf16(p[n*4+0], p[n*4+1]);
      pk2.y = cvt_pk_bf16(p[n*4+2], p[n*4+3]);
      *(uint2*)(pb + ((n * 32 + lg * 8) ^ (rho << 4))) = pk2;
    }
    asm volatile("s_waitcnt lgkmcnt(0)" ::: "memory");
    __builtin_amdgcn_sched_barrier(0);

    // ---- PV ----
    bf16x8 ap0 = *(const bf16x8*)(pb + ((lg ^ rho) << 4));
    bf16x8 ap1 = *(const bf16x8*)(pb + (((4 + lg) ^ rho) << 4));
    const char* vbc = (const char*)vbuf[cur];
    __builtin_amdgcn_s_setprio(1);
#pragma unroll
    for (int nd = 0; nd < 4; ++nd) {
      const char* rb = vbc + (nd * 16 + lr) * 128;
      bf16x8 v0 = *(const bf16x8*)(rb + ((lg ^ rho) << 4));
      bf16x8 v1 = *(const bf16x8*)(rb + (((4 + lg) ^ rho) << 4));
      acc_o[nd] = mfma16(ap0, v0, acc_o[nd]);
      acc_o[nd] = mfma16(ap1, v1, acc_o[nd]);
    }
    __builtin_amdgcn_s_setprio(0);
    __syncthreads();
  }
#undef STAGE_KV

  float inv[4];
#pragma unroll
  for (int r = 0; r < 4; ++r) inv[r] = 1.0f / __shfl(l_run, lg * 4 + r, 64);
#pragma unroll
  for (int r = 0; r < 4; ++r) {
    int gr = i0 + w * 16 + lg * 4 + r;
#pragma unroll
    for (int nd = 0; nd < 4; ++nd)
      att[(size_t)(b * S_LEN + gr) * DMODEL + h * DH + nd * 16 + lr] =
          f2b(acc_o[nd][r] * inv[r]);
  }
}

// ---------------- host launch ----------------
extern "C" void kernel_launch(void* const* d_in, const int* in_sizes, int n_in,
                              void* d_out, int out_size, void* d_ws, size_t ws_size,
                              hipStream_t stream) {
  const float* tokens = (const float*)d_in[0];
  const float* ab     = (const float*)d_in[1];
  const float* mc     = (const float*)d_in[2];
  const unsigned char* kp = (const unsigned char*)d_in[3];
  const float* ln1g = (const float*)d_in[4];
  const float* ln1b = (const float*)d_in[5];
  const float* Wq = (const float*)d_in[6];
  const float* bq = (const float*)d_in[7];
  const float* Wk = (const float*)d_in[8];
  const float* bk = (const float*)d_in[9];
  const float* Wv = (const float*)d_in[10];
  const float* bv = (const float*)d_in[11];
  const float* Wo = (const float*)d_in[12];
  const float* bo = (const float*)d_in[13];
  const float* Ws = (const float*)d_in[14];
  const float* bs = (const float*)d_in[15];
  const float* Wm = (const float*)d_in[16];
  const float* bm = (const float*)d_in[17];
  const float* ln2g = (const float*)d_in[18];
  const float* ln2b = (const float*)d_in[19];
  const float* W1 = (const float*)d_in[20];
  const float* b1 = (const float*)d_in[21];
  const float* W2 = (const float*)d_in[22];
  const float* b2 = (const float*)d_in[23];
  float* out = (float*)d_out;

  int B = in_sizes[0] / (S_LEN * DMODEL);
  int M = B * S_LEN;

  char* ws = (char*)d_ws;
  ushort_t* nb  = (ushort_t*)(ws + 0);
  ushort_t* qb  = (ushort_t*)(ws + (size_t)8388608);
  ushort_t* kb  = (ushort_t*)(ws + (size_t)16777216);
  ushort_t* vtb = (ushort_t*)(ws + (size_t)25165824);
  ushort_t* ff1 = (ushort_t*)(ws + 0);  // aliases n/q/k/vt (dead by then)
  ushort_t* wt_q = (ushort_t*)(ws + (size_t)33554432);
  ushort_t* wt_k = (ushort_t*)(ws + (size_t)35651584);
  ushort_t* wt_v = (ushort_t*)(ws + (size_t)37748736);
  ushort_t* wt_o = (ushort_t*)(ws + (size_t)39845888);
  ushort_t* wt_1 = (ushort_t*)(ws + (size_t)41943040);
  ushort_t* wt_2 = (ushort_t*)(ws + (size_t)50331648);
  ushort_t* attb = (ushort_t*)(ws + (size_t)58720256);
  float*    xb   = (float*)   (ws + (size_t)67108864);
  ushort_t* hb   = (ushort_t*)(ws + (size_t)83886080);
  ushort_t* bp   = (ushort_t*)(ws + (size_t)92274688);

  tconv6<<<12288, dim3(32, 8), 0, stream>>>(Wq, Wk, Wv, Wo, W1, W2,
                                            wt_q, wt_k, wt_v, wt_o, wt_1, wt_2);

  ln_kernel<<<M, 256, 0, stream>>>(tokens, ln1g, ln1b, nb);

  bias_head_kernel<<<M, 256, 0, stream>>>(ab, mc, kp, Ws, bs, Wm, bm, bp);

  gemm_bt<4><<<dim3(24, M / 128), 256, 0, stream>>>(
      nb, wt_q, bq, bk, bv, qb, kb, vtb, M, 3 * DMODEL, DMODEL);

  attn_kernel<<<dim3(S_LEN / 64, B * NH), 256, 0, stream>>>(qb, kb, vtb, bp, attb);

  gemm64_res<<<dim3(16, M / 128), 256, 0, stream>>>(
      attb, wt_o, bo, tokens, xb, M, DMODEL, DMODEL);

  ln_kernel<<<M, 256, 0, stream>>>(xb, ln2g, ln2b, hb);

  gemm_bt<3><<<dim3(32, M / 128), 256, 0, stream>>>(
      hb, wt_1, b1, nullptr, nullptr, ff1, nullptr, nullptr, M, FFDIM, DMODEL);

  gemm64_res<<<dim3(16, M / 128), 256, 0, stream>>>(
      ff1, wt_2, b2, xb, out, M, DMODEL, FFDIM);
}

// Round 4
// 643.900 us; speedup vs baseline: 1.6242x; 1.6242x over previous
//
#include <hip/hip_runtime.h>

#define S_LEN 2048
#define DMODEL 1024
#define NH 16
#define DH 64
#define FFDIM 4096

typedef __bf16 bf16x8 __attribute__((ext_vector_type(8)));
typedef float f32x4 __attribute__((ext_vector_type(4)));
typedef unsigned short ushort_t;

#define AS1 __attribute__((address_space(1)))
#define AS3 __attribute__((address_space(3)))

__device__ __forceinline__ void gll16(const void* g, void* l) {
  __builtin_amdgcn_global_load_lds((AS1 const void*)g, (AS3 void*)l, 16, 0, 0);
}

__device__ __forceinline__ unsigned short f2b(float f){
  unsigned u = __builtin_bit_cast(unsigned, f);
  u = (u + 0x7FFFu + ((u >> 16) & 1u)) >> 16;
  return (unsigned short)u;
}

__device__ __forceinline__ float b2f(unsigned short us){
  return __builtin_bit_cast(float, (unsigned)us << 16);
}

// packed bf16 convert: dst.lo = bf16(lo), dst.hi = bf16(hi) (RNE)
__device__ __forceinline__ unsigned cvt_pk_bf16(float lo, float hi){
  unsigned r;
  asm("v_cvt_pk_bf16_f32 %0, %1, %2" : "=v"(r) : "v"(lo), "v"(hi));
  return r;
}

__device__ __forceinline__ float gelu_exact(float x){
  return 0.5f * x * (1.0f + erff(x * 0.70710678118654752f));
}

__device__ __forceinline__ f32x4 mfma16(bf16x8 a, bf16x8 b, f32x4 c){
  return __builtin_amdgcn_mfma_f32_16x16x32_bf16(a, b, c, 0, 0, 0);
}

// ---------------- all 6 weight transposes in ONE launch ----------------
__global__ __launch_bounds__(256) void tconv6(
    const float* __restrict__ s0, const float* __restrict__ s1,
    const float* __restrict__ s2, const float* __restrict__ s3,
    const float* __restrict__ s4, const float* __restrict__ s5,
    ushort_t* __restrict__ d0, ushort_t* __restrict__ d1,
    ushort_t* __restrict__ d2, ushort_t* __restrict__ d3,
    ushort_t* __restrict__ d4, ushort_t* __restrict__ d5)
{
  __shared__ float tile[32][33];
  int bx = blockIdx.x;
  const float* W; ushort_t* Wt; int K, N, n0, k0;
  if (bx < 4096) {
    int seg = bx >> 10, t_ = bx & 1023;
    W = (seg == 0) ? s0 : (seg == 1) ? s1 : (seg == 2) ? s2 : s3;
    Wt = (seg == 0) ? d0 : (seg == 1) ? d1 : (seg == 2) ? d2 : d3;
    K = 1024; N = 1024; n0 = (t_ & 31) * 32; k0 = (t_ >> 5) * 32;
  } else if (bx < 8192) {
    int t_ = bx - 4096;
    W = s4; Wt = d4; K = 1024; N = 4096;
    n0 = (t_ & 127) * 32; k0 = (t_ >> 7) * 32;
  } else {
    int t_ = bx - 8192;
    W = s5; Wt = d5; K = 4096; N = 1024;
    n0 = (t_ & 31) * 32; k0 = (t_ >> 5) * 32;
  }
  int tx = threadIdx.x, ty = threadIdx.y;
#pragma unroll
  for (int i = 0; i < 4; ++i)
    tile[ty + i*8][tx] = W[(size_t)(k0 + ty + i*8) * N + n0 + tx];
  __syncthreads();
#pragma unroll
  for (int i = 0; i < 4; ++i)
    Wt[(size_t)(n0 + ty + i*8) * K + k0 + tx] = f2b(tile[tx][ty + i*8]);
}

// ---------------- layernorm (fp32 in) -> bf16 out ----------------
__global__ __launch_bounds__(256) void ln_kernel(
    const float* __restrict__ x, const float* __restrict__ g,
    const float* __restrict__ bt, ushort_t* __restrict__ out)
{
  int row = blockIdx.x;
  int t = threadIdx.x;
  const float4 v = *(const float4*)&x[(size_t)row * DMODEL + t * 4];
  float s = v.x + v.y + v.z + v.w;
  float s2 = v.x*v.x + v.y*v.y + v.z*v.z + v.w*v.w;
#pragma unroll
  for (int d = 1; d < 64; d <<= 1) {
    s  += __shfl_xor(s,  d, 64);
    s2 += __shfl_xor(s2, d, 64);
  }
  __shared__ float red[8];
  int w = t >> 6;
  if ((t & 63) == 0) { red[w] = s; red[4 + w] = s2; }
  __syncthreads();
  s  = red[0] + red[1] + red[2] + red[3];
  s2 = red[4] + red[5] + red[6] + red[7];
  float mean = s * (1.0f / DMODEL);
  float var  = s2 * (1.0f / DMODEL) - mean * mean;
  float rstd = rsqrtf(var + 1e-5f);
  float4 gg = *(const float4*)&g[t * 4];
  float4 bb = *(const float4*)&bt[t * 4];
  ushort4 o;
  o.x = f2b((v.x - mean) * rstd * gg.x + bb.x);
  o.y = f2b((v.y - mean) * rstd * gg.y + bb.y);
  o.z = f2b((v.z - mean) * rstd * gg.z + bb.z);
  o.w = f2b((v.w - mean) * rstd * gg.w + bb.w);
  *(ushort4*)&out[(size_t)row * DMODEL + t * 4] = o;
}

// ---------------- bias precompute: per-head bf16, ROW-MAJOR [bh][i][j] ----------------
// Coalesced: lane t handles j = t*8..t*8+7, writes one uint4 per head.
// kp mask folded in (-1e9).
__global__ __launch_bounds__(256) void bias_head_kernel(
    const float* __restrict__ ab, const float* __restrict__ mc,
    const unsigned char* __restrict__ kp,
    const float* __restrict__ Ws, const float* __restrict__ bs,
    const float* __restrict__ Wm, const float* __restrict__ bm,
    ushort_t* __restrict__ bp)
{
  int bi = blockIdx.x;            // b*S + i
  int b = bi >> 11;
  int i = bi & (S_LEN - 1);
  int t = threadIdx.x;
  int j0 = t * 8;
  float av[24];
  const float4* A4 = (const float4*)(ab + ((size_t)bi * S_LEN + j0) * 3);
#pragma unroll
  for (int u = 0; u < 6; ++u) {
    float4 x = A4[u];
    av[u*4] = x.x; av[u*4+1] = x.y; av[u*4+2] = x.z; av[u*4+3] = x.w;
  }
  float mv[8];
  const float4* M4 = (const float4*)(mc + (size_t)bi * S_LEN + j0);
#pragma unroll
  for (int u = 0; u < 2; ++u) {
    float4 x = M4[u];
    mv[u*4] = x.x; mv[u*4+1] = x.y; mv[u*4+2] = x.z; mv[u*4+3] = x.w;
  }
  unsigned long long kq = *(const unsigned long long*)(kp + (size_t)b * S_LEN + j0);
#pragma unroll
  for (int h = 0; h < NH; ++h) {
    float w0 = Ws[h], w1 = Ws[NH + h], w2 = Ws[2*NH + h];
    float wm = Wm[h], cc = bs[h] + bm[h];
    float v[8];
#pragma unroll
    for (int j = 0; j < 8; ++j) {
      float vv = av[j*3]*w0 + av[j*3+1]*w1 + av[j*3+2]*w2 + mv[j]*wm + cc;
      if ((kq >> (8*j)) & 1ull) vv = -1e9f;
      v[j] = vv;
    }
    uint4 pk;
    pk.x = cvt_pk_bf16(v[0], v[1]);
    pk.y = cvt_pk_bf16(v[2], v[3]);
    pk.z = cvt_pk_bf16(v[4], v[5]);
    pk.w = cvt_pk_bf16(v[6], v[7]);
    *(uint4*)&bp[((size_t)(b*NH + h) * S_LEN + i) * S_LEN + j0] = pk;
  }
}

// ---------------- bf16 GEMM, 128x128 tile, 2-phase dbuf ----------------
// MODE 3: out bf16 = gelu(acc + bias)
// MODE 4: fused QKV: N=3072; seg0->o0 bf16, seg1->o1 bf16, seg2->o2 vt layout
template<int MODE>
__global__ __launch_bounds__(256) void gemm_bt(
    const ushort_t* __restrict__ A, const ushort_t* __restrict__ Bt,
    const float* __restrict__ b0p, const float* __restrict__ b1p,
    const float* __restrict__ b2p,
    void* __restrict__ o0, void* __restrict__ o1, void* __restrict__ o2,
    int M, int N, int K)
{
  __shared__ ushort_t sh[2][8192];
  int t = threadIdx.x;
  int m0 = blockIdx.y * 128, n0 = blockIdx.x * 128;
  int w = t >> 6, l = t & 63, lr = l & 15, lg = l >> 4;
  int wr = (w >> 1) * 64, wc = (w & 1) * 64;

  const ushort_t* srcp[4];
  int dsto[4];
#pragma unroll
  for (int j = 0; j < 4; ++j) {
    int c = j * 4 + w;
    int o = c * 1024 + l * 16;
    if (c < 8)
      srcp[j] = &A[(size_t)(m0 + (o >> 6)) * K + ((o & 63) >> 1)];
    else {
      int o2 = o - 8192;
      srcp[j] = &Bt[(size_t)(n0 + (o2 >> 6)) * K + ((o2 & 63) >> 1)];
    }
    dsto[j] = o;
  }

#define GSTAGE(bi, kk) do { \
  _Pragma("unroll") \
  for (int j = 0; j < 4; ++j) gll16(srcp[j] + (kk), (char*)sh[bi] + dsto[j]); \
} while (0)

  GSTAGE(0, 0);
  __syncthreads();
  f32x4 acc[4][4] = {};
  int cur = 0;
  for (int k0 = 0; k0 < K; k0 += 32) {
    if (k0 + 32 < K) GSTAGE(cur ^ 1, k0 + 32);
    const ushort_t* s = sh[cur];
    bf16x8 af[4], bfr[4];
#pragma unroll
    for (int a = 0; a < 4; ++a)
      af[a] = *(const bf16x8*)&s[(wr + a * 16 + lr) * 32 + lg * 8];
#pragma unroll
    for (int b = 0; b < 4; ++b)
      bfr[b] = *(const bf16x8*)&s[4096 + (wc + b * 16 + lr) * 32 + lg * 8];
    __builtin_amdgcn_s_setprio(1);
#pragma unroll
    for (int a = 0; a < 4; ++a)
#pragma unroll
      for (int b = 0; b < 4; ++b)
        acc[a][b] = mfma16(af[a], bfr[b], acc[a][b]);
    __builtin_amdgcn_s_setprio(0);
    __syncthreads();
    cur ^= 1;
  }
#undef GSTAGE

  if (MODE == 3) {
    ushort_t* out = (ushort_t*)o0;
#pragma unroll
    for (int a = 0; a < 4; ++a)
#pragma unroll
      for (int b = 0; b < 4; ++b) {
        int gn = n0 + wc + b * 16 + lr;
        float bv = b0p[gn];
#pragma unroll
        for (int r = 0; r < 4; ++r) {
          int gm = m0 + wr + a * 16 + lg * 4 + r;
          out[(size_t)gm * N + gn] = f2b(gelu_exact(acc[a][b][r] + bv));
        }
      }
  } else { // MODE 4
    int seg = n0 >> 10;
    int nb0 = n0 & 1023;
    const float* bi = (seg == 0) ? b0p : (seg == 1) ? b1p : b2p;
    if (seg < 2) {
      ushort_t* out = (ushort_t*)((seg == 0) ? o0 : o1);
#pragma unroll
      for (int a = 0; a < 4; ++a)
#pragma unroll
        for (int b = 0; b < 4; ++b) {
          int nn = nb0 + wc + b * 16 + lr;
          float bv = bi[nn];
#pragma unroll
          for (int r = 0; r < 4; ++r) {
            int gm = m0 + wr + a * 16 + lg * 4 + r;
            out[(size_t)gm * DMODEL + nn] = f2b(acc[a][b][r] + bv);
          }
        }
    } else {
      ushort_t* out = (ushort_t*)o2;    // vt[b][h][dh][s]
#pragma unroll
      for (int a = 0; a < 4; ++a)
#pragma unroll
        for (int b = 0; b < 4; ++b) {
          int nn = nb0 + wc + b * 16 + lr;
          int gm = m0 + wr + a * 16 + lg * 4;
          float bv = bi[nn];
          ushort4 pk;
          pk.x = f2b(acc[a][b][0] + bv);
          pk.y = f2b(acc[a][b][1] + bv);
          pk.z = f2b(acc[a][b][2] + bv);
          pk.w = f2b(acc[a][b][3] + bv);
          size_t addr = (((size_t)(gm >> 11) * NH + (nn >> 6)) * DH + (nn & 63)) * S_LEN
                        + (gm & (S_LEN - 1));
          *(ushort4*)&out[addr] = pk;
        }
    }
  }
}

// ---------------- bf16 GEMM, 128x64 tile, fp32 out = acc + bias + res ----------------
__global__ __launch_bounds__(256) void gemm64_res(
    const ushort_t* __restrict__ A, const ushort_t* __restrict__ Bt,
    const float* __restrict__ bias, const float* __restrict__ res,
    float* __restrict__ out, int M, int N, int K)
{
  __shared__ ushort_t sh[2][6144];   // A [128][32] @0, B [64][32] @4096 (ushorts)
  int t = threadIdx.x;
  int m0 = blockIdx.y * 128, n0 = blockIdx.x * 64;
  int w = t >> 6, l = t & 63, lr = l & 15, lg = l >> 4;
  int wr = (w >> 1) * 64, wc = (w & 1) * 32;

  const ushort_t* srcp[3];
  int dsto[3];
#pragma unroll
  for (int j = 0; j < 3; ++j) {
    int c = j * 4 + w;
    int o = c * 1024 + l * 16;
    if (c < 8)
      srcp[j] = &A[(size_t)(m0 + (o >> 6)) * K + ((o & 63) >> 1)];
    else {
      int o2 = o - 8192;
      srcp[j] = &Bt[(size_t)(n0 + (o2 >> 6)) * K + ((o2 & 63) >> 1)];
    }
    dsto[j] = o;
  }

#define GSTAGE64(bi, kk) do { \
  _Pragma("unroll") \
  for (int j = 0; j < 3; ++j) gll16(srcp[j] + (kk), (char*)sh[bi] + dsto[j]); \
} while (0)

  GSTAGE64(0, 0);
  __syncthreads();
  f32x4 acc[4][2] = {};
  int cur = 0;
  for (int k0 = 0; k0 < K; k0 += 32) {
    if (k0 + 32 < K) GSTAGE64(cur ^ 1, k0 + 32);
    const ushort_t* s = sh[cur];
    bf16x8 af[4], bfr[2];
#pragma unroll
    for (int a = 0; a < 4; ++a)
      af[a] = *(const bf16x8*)&s[(wr + a * 16 + lr) * 32 + lg * 8];
#pragma unroll
    for (int b = 0; b < 2; ++b)
      bfr[b] = *(const bf16x8*)&s[4096 + (wc + b * 16 + lr) * 32 + lg * 8];
    __builtin_amdgcn_s_setprio(1);
#pragma unroll
    for (int a = 0; a < 4; ++a)
#pragma unroll
      for (int b = 0; b < 2; ++b)
        acc[a][b] = mfma16(af[a], bfr[b], acc[a][b]);
    __builtin_amdgcn_s_setprio(0);
    __syncthreads();
    cur ^= 1;
  }
#undef GSTAGE64

#pragma unroll
  for (int a = 0; a < 4; ++a)
#pragma unroll
    for (int b = 0; b < 2; ++b) {
      int gn = n0 + wc + b * 16 + lr;
      float bv = bias[gn];
#pragma unroll
      for (int r = 0; r < 4; ++r) {
        int gm = m0 + wr + a * 16 + lg * 4 + r;
        out[(size_t)gm * N + gn] = acc[a][b][r] + bv + res[(size_t)gm * N + gn];
      }
    }
}

// ---------------- fused flash attention, swapped-QK, swizzled LDS, dbuf ----------------
// bias: row-major per-head bf16 bp[bh][i][j]; lane reads uint2 (4 j's, r-contiguous)
__global__ __launch_bounds__(256) void attn_kernel(
    const ushort_t* __restrict__ q, const ushort_t* __restrict__ k,
    const ushort_t* __restrict__ vt, const ushort_t* __restrict__ bp,
    ushort_t* __restrict__ att)
{
  __shared__ ushort_t kbuf[2][4096];   // [64 rows][64 cols] bf16, content pre-swizzled
  __shared__ ushort_t vbuf[2][4096];
  __shared__ ushort_t p_lds[4096];     // [64 q][64 j] bf16, swizzled
  int bh = blockIdx.y;
  int b = bh >> 4, h = bh & 15;
  int i0 = blockIdx.x * 64;
  int t = threadIdx.x, w = t >> 6, l = t & 63;
  int lr = l & 15, lg = l >> 4;
  int rho = lr & 7;
  const float scale = 0.125f;  // DH^-0.5

  // staging geometry (per thread)
  int srow0 = t >> 3, srow1 = 32 + (t >> 3);
  int c16 = t & 7;
  size_t kb0 = (size_t)b * S_LEN * DMODEL + h * DH;
  size_t vb0 = (size_t)(b * NH + h) * DH * S_LEN;
  size_t koff0 = (size_t)srow0 * DMODEL + ((c16 ^ (srow0 & 7)) << 3);
  size_t koff1 = (size_t)srow1 * DMODEL + ((c16 ^ (srow1 & 7)) << 3);
  size_t voff0 = (size_t)srow0 * S_LEN + ((c16 ^ (srow0 & 7)) << 3);
  size_t voff1 = (size_t)srow1 * S_LEN + ((c16 ^ (srow1 & 7)) << 3);
  int do0 = t * 8, do1 = 2048 + t * 8;

#define STAGE_KV(bi, j0_) do { \
  size_t kr = kb0 + (size_t)(j0_) * DMODEL; \
  size_t vr = vb0 + (size_t)(j0_); \
  gll16(k + kr + koff0, &kbuf[bi][do0]); \
  gll16(k + kr + koff1, &kbuf[bi][do1]); \
  gll16(vt + vr + voff0, &vbuf[bi][do0]); \
  gll16(vt + vr + voff1, &vbuf[bi][do1]); \
} while (0)

  // Q fragments (B-operand): lane lr -> q-row, lg -> k-chunk
  int qrow = i0 + w * 16 + lr;
  size_t qbase = (size_t)(b * S_LEN + qrow) * DMODEL + h * DH;
  bf16x8 aq0 = *(const bf16x8*)&q[qbase + lg * 8];
  bf16x8 aq1 = *(const bf16x8*)&q[qbase + 32 + lg * 8];

  // row-major per-head bias: lane owns q-row `qrow`; per tile reads 4 uint2
  size_t rbias = ((size_t)bh * S_LEN + qrow) * S_LEN;

  f32x4 acc_o[4] = {};
  float m_run = -1e30f, l_run = 0.0f;

  STAGE_KV(0, 0);
  __syncthreads();

  for (int jt = 0; jt < S_LEN / 64; ++jt) {
    int cur = jt & 1;
    if (jt + 1 < S_LEN / 64) STAGE_KV(cur ^ 1, (jt + 1) * 64);

    // ---- QK^T (swapped: A=K rows, B=Q) ----
    const char* kbc = (const char*)kbuf[cur];
    f32x4 acc_s[4] = {};
    __builtin_amdgcn_s_setprio(1);
#pragma unroll
    for (int n = 0; n < 4; ++n) {
      const char* rb = kbc + (n * 16 + lr) * 128;
      bf16x8 k0 = *(const bf16x8*)(rb + ((lg ^ rho) << 4));
      bf16x8 k1 = *(const bf16x8*)(rb + (((4 + lg) ^ rho) << 4));
      acc_s[n] = mfma16(k0, aq0, acc_s[n]);
      acc_s[n] = mfma16(k1, aq1, acc_s[n]);
    }
    __builtin_amdgcn_s_setprio(0);

    // ---- bias + online softmax (lane owns one q-row, 16 k-values) ----
    float p[16];
#pragma unroll
    for (int n = 0; n < 4; ++n) {
      uint2 raw = *(const uint2*)&bp[rbias + jt * 64 + n * 16 + lg * 4];
      p[n*4+0] = fmaf(acc_s[n][0], scale, b2f((unsigned short)(raw.x & 0xFFFF)));
      p[n*4+1] = fmaf(acc_s[n][1], scale, b2f((unsigned short)(raw.x >> 16)));
      p[n*4+2] = fmaf(acc_s[n][2], scale, b2f((unsigned short)(raw.y & 0xFFFF)));
      p[n*4+3] = fmaf(acc_s[n][3], scale, b2f((unsigned short)(raw.y >> 16)));
    }
    float t8[8], t4[4];
#pragma unroll
    for (int i = 0; i < 8; ++i) t8[i] = fmaxf(p[i], p[i + 8]);
#pragma unroll
    for (int i = 0; i < 4; ++i) t4[i] = fmaxf(t8[i], t8[i + 4]);
    float mx = fmaxf(fmaxf(t4[0], t4[1]), fmaxf(t4[2], t4[3]));
    mx = fmaxf(mx, __shfl_xor(mx, 16, 64));
    mx = fmaxf(mx, __shfl_xor(mx, 32, 64));
    float mnew = fmaxf(m_run, mx);
    float sf = __expf(m_run - mnew);
    m_run = mnew;
#pragma unroll
    for (int i = 0; i < 16; ++i) p[i] = __expf(p[i] - mnew);
    float s8[8], s4[4];
#pragma unroll
    for (int i = 0; i < 8; ++i) s8[i] = p[i] + p[i + 8];
#pragma unroll
    for (int i = 0; i < 4; ++i) s4[i] = s8[i] + s8[i + 4];
    float ls = (s4[0] + s4[1]) + (s4[2] + s4[3]);
    ls += __shfl_xor(ls, 16, 64);
    ls += __shfl_xor(ls, 32, 64);
    l_run = l_run * sf + ls;

    // broadcast rescale factor to acc_o rows (row = lg*4 + r, held by lane lr = that row)
    float sfr[4];
#pragma unroll
    for (int r = 0; r < 4; ++r) sfr[r] = __shfl(sf, lg * 4 + r, 64);
#pragma unroll
    for (int nd = 0; nd < 4; ++nd)
#pragma unroll
      for (int r = 0; r < 4; ++r) acc_o[nd][r] *= sfr[r];

    // ---- pack P -> swizzled LDS (wave-private rows) ----
    char* pb = (char*)p_lds + (w * 16 + lr) * 128;
#pragma unroll
    for (int n = 0; n < 4; ++n) {
      uint2 pk2;
      pk2.x = cvt_pk_bf16(p[n*4+0], p[n*4+1]);
      pk2.y = cvt_pk_bf16(p[n*4+2], p[n*4+3]);
      *(uint2*)(pb + ((n * 32 + lg * 8) ^ (rho << 4))) = pk2;
    }
    asm volatile("s_waitcnt lgkmcnt(0)" ::: "memory");
    __builtin_amdgcn_sched_barrier(0);

    // ---- PV ----
    bf16x8 ap0 = *(const bf16x8*)(pb + ((lg ^ rho) << 4));
    bf16x8 ap1 = *(const bf16x8*)(pb + (((4 + lg) ^ rho) << 4));
    const char* vbc = (const char*)vbuf[cur];
    __builtin_amdgcn_s_setprio(1);
#pragma unroll
    for (int nd = 0; nd < 4; ++nd) {
      const char* rb = vbc + (nd * 16 + lr) * 128;
      bf16x8 v0 = *(const bf16x8*)(rb + ((lg ^ rho) << 4));
      bf16x8 v1 = *(const bf16x8*)(rb + (((4 + lg) ^ rho) << 4));
      acc_o[nd] = mfma16(ap0, v0, acc_o[nd]);
      acc_o[nd] = mfma16(ap1, v1, acc_o[nd]);
    }
    __builtin_amdgcn_s_setprio(0);
    __syncthreads();
  }
#undef STAGE_KV

  float inv[4];
#pragma unroll
  for (int r = 0; r < 4; ++r) inv[r] = 1.0f / __shfl(l_run, lg * 4 + r, 64);
#pragma unroll
  for (int r = 0; r < 4; ++r) {
    int gr = i0 + w * 16 + lg * 4 + r;
#pragma unroll
    for (int nd = 0; nd < 4; ++nd)
      att[(size_t)(b * S_LEN + gr) * DMODEL + h * DH + nd * 16 + lr] =
          f2b(acc_o[nd][r] * inv[r]);
  }
}

// ---------------- host launch ----------------
extern "C" void kernel_launch(void* const* d_in, const int* in_sizes, int n_in,
                              void* d_out, int out_size, void* d_ws, size_t ws_size,
                              hipStream_t stream) {
  const float* tokens = (const float*)d_in[0];
  const float* ab     = (const float*)d_in[1];
  const float* mc     = (const float*)d_in[2];
  const unsigned char* kp = (const unsigned char*)d_in[3];
  const float* ln1g = (const float*)d_in[4];
  const float* ln1b = (const float*)d_in[5];
  const float* Wq = (const float*)d_in[6];
  const float* bq = (const float*)d_in[7];
  const float* Wk = (const float*)d_in[8];
  const float* bk = (const float*)d_in[9];
  const float* Wv = (const float*)d_in[10];
  const float* bv = (const float*)d_in[11];
  const float* Wo = (const float*)d_in[12];
  const float* bo = (const float*)d_in[13];
  const float* Ws = (const float*)d_in[14];
  const float* bs = (const float*)d_in[15];
  const float* Wm = (const float*)d_in[16];
  const float* bm = (const float*)d_in[17];
  const float* ln2g = (const float*)d_in[18];
  const float* ln2b = (const float*)d_in[19];
  const float* W1 = (const float*)d_in[20];
  const float* b1 = (const float*)d_in[21];
  const float* W2 = (const float*)d_in[22];
  const float* b2 = (const float*)d_in[23];
  float* out = (float*)d_out;

  int B = in_sizes[0] / (S_LEN * DMODEL);
  int M = B * S_LEN;

  char* ws = (char*)d_ws;
  ushort_t* nb  = (ushort_t*)(ws + 0);
  ushort_t* qb  = (ushort_t*)(ws + (size_t)8388608);
  ushort_t* kb  = (ushort_t*)(ws + (size_t)16777216);
  ushort_t* vtb = (ushort_t*)(ws + (size_t)25165824);
  ushort_t* ff1 = (ushort_t*)(ws + 0);  // aliases n/q/k/vt (dead by then)
  ushort_t* wt_q = (ushort_t*)(ws + (size_t)33554432);
  ushort_t* wt_k = (ushort_t*)(ws + (size_t)35651584);
  ushort_t* wt_v = (ushort_t*)(ws + (size_t)37748736);
  ushort_t* wt_o = (ushort_t*)(ws + (size_t)39845888);
  ushort_t* wt_1 = (ushort_t*)(ws + (size_t)41943040);
  ushort_t* wt_2 = (ushort_t*)(ws + (size_t)50331648);
  ushort_t* attb = (ushort_t*)(ws + (size_t)58720256);
  float*    xb   = (float*)   (ws + (size_t)67108864);
  ushort_t* hb   = (ushort_t*)(ws + (size_t)83886080);
  ushort_t* bp   = (ushort_t*)(ws + (size_t)92274688);

  tconv6<<<12288, dim3(32, 8), 0, stream>>>(Wq, Wk, Wv, Wo, W1, W2,
                                            wt_q, wt_k, wt_v, wt_o, wt_1, wt_2);

  ln_kernel<<<M, 256, 0, stream>>>(tokens, ln1g, ln1b, nb);

  bias_head_kernel<<<M, 256, 0, stream>>>(ab, mc, kp, Ws, bs, Wm, bm, bp);

  gemm_bt<4><<<dim3(24, M / 128), 256, 0, stream>>>(
      nb, wt_q, bq, bk, bv, qb, kb, vtb, M, 3 * DMODEL, DMODEL);

  attn_kernel<<<dim3(S_LEN / 64, B * NH), 256, 0, stream>>>(qb, kb, vtb, bp, attb);

  gemm64_res<<<dim3(16, M / 128), 256, 0, stream>>>(
      attb, wt_o, bo, tokens, xb, M, DMODEL, DMODEL);

  ln_kernel<<<M, 256, 0, stream>>>(xb, ln2g, ln2b, hb);

  gemm_bt<3><<<dim3(32, M / 128), 256, 0, stream>>>(
      hb, wt_1, b1, nullptr, nullptr, ff1, nullptr, nullptr, M, FFDIM, DMODEL);

  gemm64_res<<<dim3(16, M / 128), 256, 0, stream>>>(
      ff1, wt_2, b2, xb, out, M, DMODEL, FFDIM);
}

// Round 8
// 636.392 us; speedup vs baseline: 1.6433x; 1.0118x over previous
//
#include <hip/hip_runtime.h>

#define S_LEN 2048
#define DMODEL 1024
#define NH 16
#define DH 64
#define FFDIM 4096

typedef __bf16 bf16x8 __attribute__((ext_vector_type(8)));
typedef float f32x4 __attribute__((ext_vector_type(4)));
typedef unsigned short ushort_t;

#define AS1 __attribute__((address_space(1)))
#define AS3 __attribute__((address_space(3)))

__device__ __forceinline__ void gll16(const void* g, void* l) {
  __builtin_amdgcn_global_load_lds((AS1 const void*)g, (AS3 void*)l, 16, 0, 0);
}

__device__ __forceinline__ unsigned short f2b(float f){
  unsigned u = __builtin_bit_cast(unsigned, f);
  u = (u + 0x7FFFu + ((u >> 16) & 1u)) >> 16;
  return (unsigned short)u;
}

__device__ __forceinline__ float b2f(unsigned short us){
  return __builtin_bit_cast(float, (unsigned)us << 16);
}

// packed bf16 convert: dst.lo = bf16(lo), dst.hi = bf16(hi) (RNE)
__device__ __forceinline__ unsigned cvt_pk_bf16(float lo, float hi){
  unsigned r;
  asm("v_cvt_pk_bf16_f32 %0, %1, %2" : "=v"(r) : "v"(lo), "v"(hi));
  return r;
}

__device__ __forceinline__ float gelu_exact(float x){
  return 0.5f * x * (1.0f + erff(x * 0.70710678118654752f));
}

__device__ __forceinline__ f32x4 mfma16(bf16x8 a, bf16x8 b, f32x4 c){
  return __builtin_amdgcn_mfma_f32_16x16x32_bf16(a, b, c, 0, 0, 0);
}

// ---------------- weight transpose + convert, 64x64 tiles, vectorized ----------------
// blocks 0..1023: four 1024x1024 mats (256 tiles each); 1024..2047: W1 (1024x4096);
// 2048..3071: W2 (4096x1024)
__global__ __launch_bounds__(256) void tconv64(
    const float* __restrict__ s0, const float* __restrict__ s1,
    const float* __restrict__ s2, const float* __restrict__ s3,
    const float* __restrict__ s4, const float* __restrict__ s5,
    ushort_t* __restrict__ d0, ushort_t* __restrict__ d1,
    ushort_t* __restrict__ d2, ushort_t* __restrict__ d3,
    ushort_t* __restrict__ d4, ushort_t* __restrict__ d5)
{
  __shared__ float tile[64][65];
  int bx = blockIdx.x;
  const float* W; ushort_t* Wt; int K, N, n0, k0;
  if (bx < 1024) {
    int seg = bx >> 8, t_ = bx & 255;
    W  = (seg == 0) ? s0 : (seg == 1) ? s1 : (seg == 2) ? s2 : s3;
    Wt = (seg == 0) ? d0 : (seg == 1) ? d1 : (seg == 2) ? d2 : d3;
    K = 1024; N = 1024; n0 = (t_ & 15) * 64; k0 = (t_ >> 4) * 64;
  } else if (bx < 2048) {
    int t_ = bx - 1024;
    W = s4; Wt = d4; K = 1024; N = 4096;
    n0 = (t_ & 63) * 64; k0 = (t_ >> 6) * 64;
  } else {
    int t_ = bx - 2048;
    W = s5; Wt = d5; K = 4096; N = 1024;
    n0 = (t_ & 15) * 64; k0 = (t_ >> 4) * 64;
  }
  int t = threadIdx.x;
  int lrow = t >> 4, lcol = (t & 15) * 4;
#pragma unroll
  for (int i = 0; i < 4; ++i) {
    float4 v = *(const float4*)&W[(size_t)(k0 + lrow + i * 16) * N + n0 + lcol];
    tile[lrow + i * 16][lcol]     = v.x;
    tile[lrow + i * 16][lcol + 1] = v.y;
    tile[lrow + i * 16][lcol + 2] = v.z;
    tile[lrow + i * 16][lcol + 3] = v.w;
  }
  __syncthreads();
  int orow = t >> 2, oseg = (t & 3) * 16;
  alignas(16) ushort_t ob[16];
#pragma unroll
  for (int j = 0; j < 16; ++j) ob[j] = f2b(tile[oseg + j][orow]);
  *(uint4*)&Wt[(size_t)(n0 + orow) * K + k0 + oseg]     = *(const uint4*)ob;
  *(uint4*)&Wt[(size_t)(n0 + orow) * K + k0 + oseg + 8] = *((const uint4*)ob + 1);
}

// ---------------- layernorm (fp32 in) -> bf16 out ----------------
__global__ __launch_bounds__(256) void ln_kernel(
    const float* __restrict__ x, const float* __restrict__ g,
    const float* __restrict__ bt, ushort_t* __restrict__ out)
{
  int row = blockIdx.x;
  int t = threadIdx.x;
  const float4 v = *(const float4*)&x[(size_t)row * DMODEL + t * 4];
  float s = v.x + v.y + v.z + v.w;
  float s2 = v.x*v.x + v.y*v.y + v.z*v.z + v.w*v.w;
#pragma unroll
  for (int d = 1; d < 64; d <<= 1) {
    s  += __shfl_xor(s,  d, 64);
    s2 += __shfl_xor(s2, d, 64);
  }
  __shared__ float red[8];
  int w = t >> 6;
  if ((t & 63) == 0) { red[w] = s; red[4 + w] = s2; }
  __syncthreads();
  s  = red[0] + red[1] + red[2] + red[3];
  s2 = red[4] + red[5] + red[6] + red[7];
  float mean = s * (1.0f / DMODEL);
  float var  = s2 * (1.0f / DMODEL) - mean * mean;
  float rstd = rsqrtf(var + 1e-5f);
  float4 gg = *(const float4*)&g[t * 4];
  float4 bb = *(const float4*)&bt[t * 4];
  ushort4 o;
  o.x = f2b((v.x - mean) * rstd * gg.x + bb.x);
  o.y = f2b((v.y - mean) * rstd * gg.y + bb.y);
  o.z = f2b((v.z - mean) * rstd * gg.z + bb.z);
  o.w = f2b((v.w - mean) * rstd * gg.w + bb.w);
  *(ushort4*)&out[(size_t)row * DMODEL + t * 4] = o;
}

// ---------------- bias precompute: per-head bf16, ROW-MAJOR [bh][i][j] ----------------
__global__ __launch_bounds__(256) void bias_head_kernel(
    const float* __restrict__ ab, const float* __restrict__ mc,
    const unsigned char* __restrict__ kp,
    const float* __restrict__ Ws, const float* __restrict__ bs,
    const float* __restrict__ Wm, const float* __restrict__ bm,
    ushort_t* __restrict__ bp)
{
  int bi = blockIdx.x;            // b*S + i
  int b = bi >> 11;
  int t = threadIdx.x;
  int j0 = t * 8;
  float av[24];
  const float4* A4 = (const float4*)(ab + ((size_t)bi * S_LEN + j0) * 3);
#pragma unroll
  for (int u = 0; u < 6; ++u) {
    float4 x = A4[u];
    av[u*4] = x.x; av[u*4+1] = x.y; av[u*4+2] = x.z; av[u*4+3] = x.w;
  }
  float mv[8];
  const float4* M4 = (const float4*)(mc + (size_t)bi * S_LEN + j0);
#pragma unroll
  for (int u = 0; u < 2; ++u) {
    float4 x = M4[u];
    mv[u*4] = x.x; mv[u*4+1] = x.y; mv[u*4+2] = x.z; mv[u*4+3] = x.w;
  }
  unsigned long long kq = *(const unsigned long long*)(kp + (size_t)b * S_LEN + j0);
#pragma unroll
  for (int h = 0; h < NH; ++h) {
    float w0 = Ws[h], w1 = Ws[NH + h], w2 = Ws[2*NH + h];
    float wm = Wm[h], cc = bs[h] + bm[h];
    float v[8];
#pragma unroll
    for (int j = 0; j < 8; ++j) {
      float vv = av[j*3]*w0 + av[j*3+1]*w1 + av[j*3+2]*w2 + mv[j]*wm + cc;
      if ((kq >> (8*j)) & 1ull) vv = -1e9f;
      v[j] = vv;
    }
    uint4 pk;
    pk.x = cvt_pk_bf16(v[0], v[1]);
    pk.y = cvt_pk_bf16(v[2], v[3]);
    pk.z = cvt_pk_bf16(v[4], v[5]);
    pk.w = cvt_pk_bf16(v[6], v[7]);
    *(uint4*)&bp[((size_t)(b*NH + h) * S_LEN + (bi & (S_LEN-1))) * S_LEN + j0] = pk;
  }
}

// ---------------- bf16 GEMM, 128x128 tile, 2-phase dbuf ----------------
// MODE 3: out bf16 = gelu(acc + bias)
// MODE 4: fused QKV: N=3072; seg0->o0 bf16, seg1->o1 bf16, seg2->o2 vt layout
template<int MODE>
__global__ __launch_bounds__(256) void gemm_bt(
    const ushort_t* __restrict__ A, const ushort_t* __restrict__ Bt,
    const float* __restrict__ b0p, const float* __restrict__ b1p,
    const float* __restrict__ b2p,
    void* __restrict__ o0, void* __restrict__ o1, void* __restrict__ o2,
    int M, int N, int K)
{
  __shared__ ushort_t sh[2][8192];
  int t = threadIdx.x;
  int m0 = blockIdx.y * 128, n0 = blockIdx.x * 128;
  int w = t >> 6, l = t & 63, lr = l & 15, lg = l >> 4;
  int wr = (w >> 1) * 64, wc = (w & 1) * 64;

  const ushort_t* srcp[4];
  int dsto[4];
#pragma unroll
  for (int j = 0; j < 4; ++j) {
    int c = j * 4 + w;
    int o = c * 1024 + l * 16;
    if (c < 8)
      srcp[j] = &A[(size_t)(m0 + (o >> 6)) * K + ((o & 63) >> 1)];
    else {
      int o2 = o - 8192;
      srcp[j] = &Bt[(size_t)(n0 + (o2 >> 6)) * K + ((o2 & 63) >> 1)];
    }
    dsto[j] = o;
  }

#define GSTAGE(bi, kk) do { \
  _Pragma("unroll") \
  for (int j = 0; j < 4; ++j) gll16(srcp[j] + (kk), (char*)sh[bi] + dsto[j]); \
} while (0)

  GSTAGE(0, 0);
  __syncthreads();
  f32x4 acc[4][4] = {};
  int cur = 0;
  for (int k0 = 0; k0 < K; k0 += 32) {
    if (k0 + 32 < K) GSTAGE(cur ^ 1, k0 + 32);
    const ushort_t* s = sh[cur];
    bf16x8 af[4], bfr[4];
#pragma unroll
    for (int a = 0; a < 4; ++a)
      af[a] = *(const bf16x8*)&s[(wr + a * 16 + lr) * 32 + lg * 8];
#pragma unroll
    for (int b = 0; b < 4; ++b)
      bfr[b] = *(const bf16x8*)&s[4096 + (wc + b * 16 + lr) * 32 + lg * 8];
    __builtin_amdgcn_s_setprio(1);
#pragma unroll
    for (int a = 0; a < 4; ++a)
#pragma unroll
      for (int b = 0; b < 4; ++b)
        acc[a][b] = mfma16(af[a], bfr[b], acc[a][b]);
    __builtin_amdgcn_s_setprio(0);
    __syncthreads();
    cur ^= 1;
  }
#undef GSTAGE

  if (MODE == 3) {
    ushort_t* out = (ushort_t*)o0;
#pragma unroll
    for (int a = 0; a < 4; ++a)
#pragma unroll
      for (int b = 0; b < 4; ++b) {
        int gn = n0 + wc + b * 16 + lr;
        float bv = b0p[gn];
#pragma unroll
        for (int r = 0; r < 4; ++r) {
          int gm = m0 + wr + a * 16 + lg * 4 + r;
          out[(size_t)gm * N + gn] = f2b(gelu_exact(acc[a][b][r] + bv));
        }
      }
  } else { // MODE 4
    int seg = n0 >> 10;
    int nb0 = n0 & 1023;
    const float* bi = (seg == 0) ? b0p : (seg == 1) ? b1p : b2p;
    if (seg < 2) {
      ushort_t* out = (ushort_t*)((seg == 0) ? o0 : o1);
#pragma unroll
      for (int a = 0; a < 4; ++a)
#pragma unroll
        for (int b = 0; b < 4; ++b) {
          int nn = nb0 + wc + b * 16 + lr;
          float bv = bi[nn];
#pragma unroll
          for (int r = 0; r < 4; ++r) {
            int gm = m0 + wr + a * 16 + lg * 4 + r;
            out[(size_t)gm * DMODEL + nn] = f2b(acc[a][b][r] + bv);
          }
        }
    } else {
      ushort_t* out = (ushort_t*)o2;    // vt[b][h][dh][s]
#pragma unroll
      for (int a = 0; a < 4; ++a)
#pragma unroll
        for (int b = 0; b < 4; ++b) {
          int nn = nb0 + wc + b * 16 + lr;
          int gm = m0 + wr + a * 16 + lg * 4;
          float bv = bi[nn];
          ushort4 pk;
          pk.x = f2b(acc[a][b][0] + bv);
          pk.y = f2b(acc[a][b][1] + bv);
          pk.z = f2b(acc[a][b][2] + bv);
          pk.w = f2b(acc[a][b][3] + bv);
          size_t addr = (((size_t)(gm >> 11) * NH + (nn >> 6)) * DH + (nn & 63)) * S_LEN
                        + (gm & (S_LEN - 1));
          *(ushort4*)&out[addr] = pk;
        }
    }
  }
}

// ---------------- bf16 GEMM, 128x64 tile, fp32 out = acc + bias + res ----------------
__global__ __launch_bounds__(256) void gemm64_res(
    const ushort_t* __restrict__ A, const ushort_t* __restrict__ Bt,
    const float* __restrict__ bias, const float* __restrict__ res,
    float* __restrict__ out, int M, int N, int K)
{
  __shared__ ushort_t sh[2][6144];   // A [128][32] @0, B [64][32] @4096 (ushorts)
  int t = threadIdx.x;
  int m0 = blockIdx.y * 128, n0 = blockIdx.x * 64;
  int w = t >> 6, l = t & 63, lr = l & 15, lg = l >> 4;
  int wr = (w >> 1) * 64, wc = (w & 1) * 32;

  const ushort_t* srcp[3];
  int dsto[3];
#pragma unroll
  for (int j = 0; j < 3; ++j) {
    int c = j * 4 + w;
    int o = c * 1024 + l * 16;
    if (c < 8)
      srcp[j] = &A[(size_t)(m0 + (o >> 6)) * K + ((o & 63) >> 1)];
    else {
      int o2 = o - 8192;
      srcp[j] = &Bt[(size_t)(n0 + (o2 >> 6)) * K + ((o2 & 63) >> 1)];
    }
    dsto[j] = o;
  }

#define GSTAGE64(bi, kk) do { \
  _Pragma("unroll") \
  for (int j = 0; j < 3; ++j) gll16(srcp[j] + (kk), (char*)sh[bi] + dsto[j]); \
} while (0)

  GSTAGE64(0, 0);
  __syncthreads();
  f32x4 acc[4][2] = {};
  int cur = 0;
  for (int k0 = 0; k0 < K; k0 += 32) {
    if (k0 + 32 < K) GSTAGE64(cur ^ 1, k0 + 32);
    const ushort_t* s = sh[cur];
    bf16x8 af[4], bfr[2];
#pragma unroll
    for (int a = 0; a < 4; ++a)
      af[a] = *(const bf16x8*)&s[(wr + a * 16 + lr) * 32 + lg * 8];
#pragma unroll
    for (int b = 0; b < 2; ++b)
      bfr[b] = *(const bf16x8*)&s[4096 + (wc + b * 16 + lr) * 32 + lg * 8];
    __builtin_amdgcn_s_setprio(1);
#pragma unroll
    for (int a = 0; a < 4; ++a)
#pragma unroll
      for (int b = 0; b < 2; ++b)
        acc[a][b] = mfma16(af[a], bfr[b], acc[a][b]);
    __builtin_amdgcn_s_setprio(0);
    __syncthreads();
    cur ^= 1;
  }
#undef GSTAGE64

#pragma unroll
  for (int a = 0; a < 4; ++a)
#pragma unroll
    for (int b = 0; b < 2; ++b) {
      int gn = n0 + wc + b * 16 + lr;
      float bv = bias[gn];
#pragma unroll
      for (int r = 0; r < 4; ++r) {
        int gm = m0 + wr + a * 16 + lg * 4 + r;
        out[(size_t)gm * N + gn] = acc[a][b][r] + bv + res[(size_t)gm * N + gn];
      }
    }
}

// ---------------- fused flash attention, swapped-QK, swizzled LDS, dbuf ----------------
// bias: row-major per-head bf16 bp[bh][i][j], register-prefetched one tile ahead.
__global__ __launch_bounds__(256) void attn_kernel(
    const ushort_t* __restrict__ q, const ushort_t* __restrict__ k,
    const ushort_t* __restrict__ vt, const ushort_t* __restrict__ bp,
    ushort_t* __restrict__ att)
{
  __shared__ ushort_t kbuf[2][4096];   // [64 rows][64 cols] bf16, content pre-swizzled
  __shared__ ushort_t vbuf[2][4096];
  __shared__ ushort_t p_lds[4096];     // [64 q][64 j] bf16, swizzled
  int bh = blockIdx.y;
  int b = bh >> 4, h = bh & 15;
  int i0 = blockIdx.x * 64;
  int t = threadIdx.x, w = t >> 6, l = t & 63;
  int lr = l & 15, lg = l >> 4;
  int rho = lr & 7;
  const float scale = 0.125f;  // DH^-0.5
  const int NT = S_LEN / 64;

  // staging geometry (per thread)
  int srow0 = t >> 3, srow1 = 32 + (t >> 3);
  int c16 = t & 7;
  size_t kb0 = (size_t)b * S_LEN * DMODEL + h * DH;
  size_t vb0 = (size_t)(b * NH + h) * DH * S_LEN;
  size_t koff0 = (size_t)srow0 * DMODEL + ((c16 ^ (srow0 & 7)) << 3);
  size_t koff1 = (size_t)srow1 * DMODEL + ((c16 ^ (srow1 & 7)) << 3);
  size_t voff0 = (size_t)srow0 * S_LEN + ((c16 ^ (srow0 & 7)) << 3);
  size_t voff1 = (size_t)srow1 * S_LEN + ((c16 ^ (srow1 & 7)) << 3);
  int do0 = t * 8, do1 = 2048 + t * 8;

#define STAGE_KV(bi, j0_) do { \
  size_t kr = kb0 + (size_t)(j0_) * DMODEL; \
  size_t vr = vb0 + (size_t)(j0_); \
  gll16(k + kr + koff0, &kbuf[bi][do0]); \
  gll16(k + kr + koff1, &kbuf[bi][do1]); \
  gll16(vt + vr + voff0, &vbuf[bi][do0]); \
  gll16(vt + vr + voff1, &vbuf[bi][do1]); \
} while (0)

  // Q fragments (B-operand): lane lr -> q-row, lg -> k-chunk
  int qrow = i0 + w * 16 + lr;
  size_t qbase = (size_t)(b * S_LEN + qrow) * DMODEL + h * DH;
  bf16x8 aq0 = *(const bf16x8*)&q[qbase + lg * 8];
  bf16x8 aq1 = *(const bf16x8*)&q[qbase + 32 + lg * 8];

  // row-major per-head bias: lane owns q-row `qrow`; per tile reads 4 uint2
  const ushort_t* bprow = bp + ((size_t)bh * S_LEN + qrow) * S_LEN + lg * 4;

  f32x4 acc_o[4] = {};
  float m_run = -1e30f, l_run = 0.0f;

  // prefetch bias tile 0 into registers
  uint2 braw[4];
#pragma unroll
  for (int n = 0; n < 4; ++n) braw[n] = *(const uint2*)(bprow + n * 16);

  STAGE_KV(0, 0);
  __syncthreads();

  for (int jt = 0; jt < NT; ++jt) {
    int cur = jt & 1;
    if (jt + 1 < NT) STAGE_KV(cur ^ 1, (jt + 1) * 64);

    // prefetch next tile's bias into regs (consumed after the barrier)
    uint2 bn[4] = {braw[0], braw[1], braw[2], braw[3]};
    if (jt + 1 < NT) {
      const ushort_t* bpt = bprow + (jt + 1) * 64;
#pragma unroll
      for (int n = 0; n < 4; ++n) bn[n] = *(const uint2*)(bpt + n * 16);
    }

    // ---- QK^T (swapped: A=K rows, B=Q) ----
    const char* kbc = (const char*)kbuf[cur];
    f32x4 acc_s[4] = {};
    __builtin_amdgcn_s_setprio(1);
#pragma unroll
    for (int n = 0; n < 4; ++n) {
      const char* rb = kbc + (n * 16 + lr) * 128;
      bf16x8 k0 = *(const bf16x8*)(rb + ((lg ^ rho) << 4));
      bf16x8 k1 = *(const bf16x8*)(rb + (((4 + lg) ^ rho) << 4));
      acc_s[n] = mfma16(k0, aq0, acc_s[n]);
      acc_s[n] = mfma16(k1, aq1, acc_s[n]);
    }
    __builtin_amdgcn_s_setprio(0);

    // ---- bias + online softmax (lane owns one q-row, 16 k-values) ----
    float p[16];
#pragma unroll
    for (int n = 0; n < 4; ++n) {
      p[n*4+0] = fmaf(acc_s[n][0], scale, b2f((unsigned short)(braw[n].x & 0xFFFF)));
      p[n*4+1] = fmaf(acc_s[n][1], scale, b2f((unsigned short)(braw[n].x >> 16)));
      p[n*4+2] = fmaf(acc_s[n][2], scale, b2f((unsigned short)(braw[n].y & 0xFFFF)));
      p[n*4+3] = fmaf(acc_s[n][3], scale, b2f((unsigned short)(braw[n].y >> 16)));
    }
    float t8[8], t4[4];
#pragma unroll
    for (int i = 0; i < 8; ++i) t8[i] = fmaxf(p[i], p[i + 8]);
#pragma unroll
    for (int i = 0; i < 4; ++i) t4[i] = fmaxf(t8[i], t8[i + 4]);
    float mx = fmaxf(fmaxf(t4[0], t4[1]), fmaxf(t4[2], t4[3]));
    mx = fmaxf(mx, __shfl_xor(mx, 16, 64));
    mx = fmaxf(mx, __shfl_xor(mx, 32, 64));

    // defer-max: skip rescale when max didn't grow past THR (wave-uniform)
    if (!__all(mx <= m_run + 8.0f)) {
      float mnew = fmaxf(m_run, mx);
      float sf = __expf(m_run - mnew);
      m_run = mnew;
      l_run *= sf;
      float sfr[4];
#pragma unroll
      for (int r = 0; r < 4; ++r) sfr[r] = __shfl(sf, lg * 4 + r, 64);
#pragma unroll
      for (int nd = 0; nd < 4; ++nd)
#pragma unroll
        for (int r = 0; r < 4; ++r) acc_o[nd][r] *= sfr[r];
    }
#pragma unroll
    for (int i = 0; i < 16; ++i) p[i] = __expf(p[i] - m_run);
    float s8[8], s4[4];
#pragma unroll
    for (int i = 0; i < 8; ++i) s8[i] = p[i] + p[i + 8];
#pragma unroll
    for (int i = 0; i < 4; ++i) s4[i] = s8[i] + s8[i + 4];
    float ls = (s4[0] + s4[1]) + (s4[2] + s4[3]);
    ls += __shfl_xor(ls, 16, 64);
    ls += __shfl_xor(ls, 32, 64);
    l_run += ls;

    // ---- pack P -> swizzled LDS (wave-private rows) ----
    char* pb = (char*)p_lds + (w * 16 + lr) * 128;
#pragma unroll
    for (int n = 0; n < 4; ++n) {
      uint2 pk2;
      pk2.x = cvt_pk_bf16(p[n*4+0], p[n*4+1]);
      pk2.y = cvt_pk_bf16(p[n*4+2], p[n*4+3]);
      *(uint2*)(pb + ((n * 32 + lg * 8) ^ (rho << 4))) = pk2;
    }
    asm volatile("s_waitcnt lgkmcnt(0)" ::: "memory");
    __builtin_amdgcn_sched_barrier(0);

    // ---- PV ----
    bf16x8 ap0 = *(const bf16x8*)(pb + ((lg ^ rho) << 4));
    bf16x8 ap1 = *(const bf16x8*)(pb + (((4 + lg) ^ rho) << 4));
    const char* vbc = (const char*)vbuf[cur];
    __builtin_amdgcn_s_setprio(1);
#pragma unroll
    for (int nd = 0; nd < 4; ++nd) {
      const char* rb = vbc + (nd * 16 + lr) * 128;
      bf16x8 v0 = *(const bf16x8*)(rb + ((lg ^ rho) << 4));
      bf16x8 v1 = *(const bf16x8*)(rb + (((4 + lg) ^ rho) << 4));
      acc_o[nd] = mfma16(ap0, v0, acc_o[nd]);
      acc_o[nd] = mfma16(ap1, v1, acc_o[nd]);
    }
    __builtin_amdgcn_s_setprio(0);
    __syncthreads();
#pragma unroll
    for (int n = 0; n < 4; ++n) braw[n] = bn[n];
  }
#undef STAGE_KV

  float inv[4];
#pragma unroll
  for (int r = 0; r < 4; ++r) inv[r] = 1.0f / __shfl(l_run, lg * 4 + r, 64);
#pragma unroll
  for (int r = 0; r < 4; ++r) {
    int gr = i0 + w * 16 + lg * 4 + r;
#pragma unroll
    for (int nd = 0; nd < 4; ++nd)
      att[(size_t)(b * S_LEN + gr) * DMODEL + h * DH + nd * 16 + lr] =
          f2b(acc_o[nd][r] * inv[r]);
  }
}

// ---------------- host launch ----------------
extern "C" void kernel_launch(void* const* d_in, const int* in_sizes, int n_in,
                              void* d_out, int out_size, void* d_ws, size_t ws_size,
                              hipStream_t stream) {
  const float* tokens = (const float*)d_in[0];
  const float* ab     = (const float*)d_in[1];
  const float* mc     = (const float*)d_in[2];
  const unsigned char* kp = (const unsigned char*)d_in[3];
  const float* ln1g = (const float*)d_in[4];
  const float* ln1b = (const float*)d_in[5];
  const float* Wq = (const float*)d_in[6];
  const float* bq = (const float*)d_in[7];
  const float* Wk = (const float*)d_in[8];
  const float* bk = (const float*)d_in[9];
  const float* Wv = (const float*)d_in[10];
  const float* bv = (const float*)d_in[11];
  const float* Wo = (const float*)d_in[12];
  const float* bo = (const float*)d_in[13];
  const float* Ws = (const float*)d_in[14];
  const float* bs = (const float*)d_in[15];
  const float* Wm = (const float*)d_in[16];
  const float* bm = (const float*)d_in[17];
  const float* ln2g = (const float*)d_in[18];
  const float* ln2b = (const float*)d_in[19];
  const float* W1 = (const float*)d_in[20];
  const float* b1 = (const float*)d_in[21];
  const float* W2 = (const float*)d_in[22];
  const float* b2 = (const float*)d_in[23];
  float* out = (float*)d_out;

  int B = in_sizes[0] / (S_LEN * DMODEL);
  int M = B * S_LEN;

  char* ws = (char*)d_ws;
  ushort_t* nb  = (ushort_t*)(ws + 0);
  ushort_t* qb  = (ushort_t*)(ws + (size_t)8388608);
  ushort_t* kb  = (ushort_t*)(ws + (size_t)16777216);
  ushort_t* vtb = (ushort_t*)(ws + (size_t)25165824);
  ushort_t* ff1 = (ushort_t*)(ws + 0);  // aliases n/q/k/vt (dead by then)
  ushort_t* wt_q = (ushort_t*)(ws + (size_t)33554432);
  ushort_t* wt_k = (ushort_t*)(ws + (size_t)35651584);
  ushort_t* wt_v = (ushort_t*)(ws + (size_t)37748736);
  ushort_t* wt_o = (ushort_t*)(ws + (size_t)39845888);
  ushort_t* wt_1 = (ushort_t*)(ws + (size_t)41943040);
  ushort_t* wt_2 = (ushort_t*)(ws + (size_t)50331648);
  ushort_t* attb = (ushort_t*)(ws + (size_t)58720256);
  float*    xb   = (float*)   (ws + (size_t)67108864);
  ushort_t* hb   = (ushort_t*)(ws + (size_t)83886080);
  ushort_t* bp   = (ushort_t*)(ws + (size_t)92274688);

  tconv64<<<3072, 256, 0, stream>>>(Wq, Wk, Wv, Wo, W1, W2,
                                    wt_q, wt_k, wt_v, wt_o, wt_1, wt_2);

  ln_kernel<<<M, 256, 0, stream>>>(tokens, ln1g, ln1b, nb);

  bias_head_kernel<<<M, 256, 0, stream>>>(ab, mc, kp, Ws, bs, Wm, bm, bp);

  gemm_bt<4><<<dim3(24, M / 128), 256, 0, stream>>>(
      nb, wt_q, bq, bk, bv, qb, kb, vtb, M, 3 * DMODEL, DMODEL);

  attn_kernel<<<dim3(S_LEN / 64, B * NH), 256, 0, stream>>>(qb, kb, vtb, bp, attb);

  gemm64_res<<<dim3(16, M / 128), 256, 0, stream>>>(
      attb, wt_o, bo, tokens, xb, M, DMODEL, DMODEL);

  ln_kernel<<<M, 256, 0, stream>>>(xb, ln2g, ln2b, hb);

  gemm_bt<3><<<dim3(32, M / 128), 256, 0, stream>>>(
      hb, wt_1, b1, nullptr, nullptr, ff1, nullptr, nullptr, M, FFDIM, DMODEL);

  gemm64_res<<<dim3(16, M / 128), 256, 0, stream>>>(
      ff1, wt_2, b2, xb, out, M, DMODEL, FFDIM);
}